// Round 25
// baseline (147.740 us; speedup 1.0000x reference)
//
#include <hip/hip_runtime.h>

// Problem constants
#define BB 4
#define CC 16
#define HH 256
#define WW 256
#define NN (HH*WW)      // 65536
#define SS 100
#define EPSV 1e-32f

// ws layout (float offsets)
#define PQ_OFF    0u                      // [8 bq][100 s][17]           = 13600
#define SPFN_OFF  13600u                  // [8 bq][100 s][16 c]         = 12800
#define PFSP_OFF  26400u                  // [4][16][65536]              = 4194304
#define PPART_OFF PFSP_OFF                // [8][128 chunk][100 s][17]   = 1740800
// PPART aliases PFSP: consumed by k_reduceP before k_pass2 overwrites.

typedef _Float16 f16x8 __attribute__((ext_vector_type(8)));
typedef float f32x4 __attribute__((ext_vector_type(4)));

// Direct global->LDS DMA. Loads never occupy VGPRs, so the compiler's
// register-pressure scheduler CANNOT serialize them with early waitcnts
// (R22/R23 post-mortem: VGPR=60 proved register double-buffers were never
// materialized). LDS dest must be wave-uniform base (+lane*16 implicit);
// global src is per-lane.
__device__ __forceinline__ void gload(const float* g, float* l) {
    __builtin_amdgcn_global_load_lds(
        (const __attribute__((address_space(1))) void*)g,
        (__attribute__((address_space(3))) void*)l, 16, 0, 0);
}

// ---------------- pass1 (K1): gload_lds-staged MFMA GEMM ----------------
// P[c,s] = sum_n pf[c,n]Q[s,n]. f32 LDS (gload can't convert; f16 cvt on
// frag read — VALU idle). Swizzle both-sides (rule #21): source col
// pre-XOR ((row&7)<<2 floats), frag-read re-XOR -> b128 at LDS peak.
// 2-phase: STAGE(next) -> compute(cur) -> syncthreads (vmcnt drain AFTER
// compute -> loads overlap compute structurally).
#define STAGE(ST, QD, PD) { \
    _Pragma("unroll") \
    for (int i_ = 0; i_ < 7; ++i_) { \
        int r0_ = wid * 28 + i_ * 4; \
        int row_ = r0_ + (lane >> 4); if (row_ > 99) row_ = 99; \
        int co_ = ((lane & 15) * 4) ^ ((row_ & 7) << 2); \
        gload(Qb + (size_t)row_ * NN + (ST) * 64 + co_, (QD) + r0_ * 64); \
    } \
    { int r0_ = wid * 4; int row_ = r0_ + (lane >> 4); \
      int co_ = ((lane & 15) * 4) ^ ((row_ & 7) << 2); \
      gload(Pb + (size_t)row_ * NN + (ST) * 64 + co_, (PD) + r0_ * 64); } }

#define MK8(a, b) {(_Float16)a.x, (_Float16)a.y, (_Float16)a.z, (_Float16)a.w, \
                   (_Float16)b.x, (_Float16)b.y, (_Float16)b.z, (_Float16)b.w}

#define KSTEP(J) { \
    float4 a0 = *(const float4*)(pc + arow + (J) * 32 + of0); \
    float4 a1 = *(const float4*)(pc + arow + (J) * 32 + of1); \
    f16x8 af = MK8(a0, a1); \
    float4 b00 = *(const float4*)(qc + brow0 + (J) * 32 + of0); \
    float4 b01 = *(const float4*)(qc + brow0 + (J) * 32 + of1); \
    f16x8 bf0 = MK8(b00, b01); \
    float4 b10 = *(const float4*)(qc + brow1 + (J) * 32 + of0); \
    float4 b11 = *(const float4*)(qc + brow1 + (J) * 32 + of1); \
    f16x8 bf1 = MK8(b10, b11); \
    acc0 = __builtin_amdgcn_mfma_f32_16x16x32_f16(af, bf0, acc0, 0, 0, 0); \
    qac0 = __builtin_amdgcn_mfma_f32_16x16x32_f16(ones, bf0, qac0, 0, 0, 0); \
    acc1 = __builtin_amdgcn_mfma_f32_16x16x32_f16(af, bf1, acc1, 0, 0, 0); \
    qac1 = __builtin_amdgcn_mfma_f32_16x16x32_f16(ones, bf1, qac1, 0, 0, 0); }

__global__ __launch_bounds__(256, 2) void k_pass1(const float* __restrict__ pf,
                                                  const float* __restrict__ Q1,
                                                  const float* __restrict__ Q2,
                                                  float* __restrict__ ws) {
    int tid = threadIdx.x, wid = tid >> 6, lane = tid & 63;
    int chunk = blockIdx.x;    // 0..127 (512-px chunk)
    int bq    = blockIdx.y;    // 0..7
    int b = bq >> 1, q = bq & 1;
    int r16 = lane & 15, g4 = lane >> 4;
    int n0 = chunk * 512;

    const float* Qb = (q ? Q2 : Q1) + (size_t)b * SS * NN + n0;
    const float* Pb = pf + (size_t)b * CC * NN + n0;

    __shared__ __align__(16) float qbufA[112 * 64];   // 28 KB
    __shared__ __align__(16) float qbufB[112 * 64];
    __shared__ __align__(16) float pbufA[16 * 64];    // 4 KB
    __shared__ __align__(16) float pbufB[16 * 64];

    // fragment read offsets (floats), swizzle matches STAGE's source XOR
    int t0 = wid;
    int t1 = (wid < 3) ? wid + 4 : 3;
    int arow  = r16 * 64;
    int brow0 = (t0 * 16 + r16) * 64;
    int brow1 = (t1 * 16 + r16) * 64;
    int sw  = (r16 & 7) << 2;
    int of0 = (g4 * 8) ^ sw;
    int of1 = (g4 * 8 + 4) ^ sw;

    f32x4 acc0 = {0.f, 0.f, 0.f, 0.f}, acc1 = {0.f, 0.f, 0.f, 0.f};
    f32x4 qac0 = {0.f, 0.f, 0.f, 0.f}, qac1 = {0.f, 0.f, 0.f, 0.f};
    const f16x8 ones = {1.f16, 1.f16, 1.f16, 1.f16, 1.f16, 1.f16, 1.f16, 1.f16};

    STAGE(0, qbufA, pbufA)
    __syncthreads();
    float* qc = qbufA; float* pc = pbufA;
    float* qn = qbufB; float* pn = pbufB;
    for (int st = 0; st < 7; ++st) {
        STAGE(st + 1, qn, pn)
        KSTEP(0) KSTEP(1)
        __syncthreads();
        float* t = qc; qc = qn; qn = t;
        t = pc; pc = pn; pn = t;
    }
    KSTEP(0) KSTEP(1)

    float* sout = ws + PPART_OFF + (size_t)(bq * 128 + chunk) * 1700;
    {
        int s0 = t0 * 16 + r16;            // 0..63, always valid
        float* o = sout + (size_t)s0 * 17 + g4 * 4;
        o[0] = acc0[0]; o[1] = acc0[1]; o[2] = acc0[2]; o[3] = acc0[3];
        if (lane < 16) sout[(size_t)s0 * 17 + 16] = qac0[0];
    }
    if (wid < 3) {
        int s1 = (wid + 4) * 16 + r16;     // 64..111
        if (s1 < 100) {
            float* o = sout + (size_t)s1 * 17 + g4 * 4;
            o[0] = acc1[0]; o[1] = acc1[1]; o[2] = acc1[2]; o[3] = acc1[3];
            if (lane < 16) sout[(size_t)s1 * 17 + 16] = qac1[0];
        }
    }
}

// ---------------- K2: reduce over 128 chunks (coalesced) ----------------
__global__ __launch_bounds__(256) void k_reduceP(float* __restrict__ ws) {
    int strip = blockIdx.x;  // 0..6
    int bq    = blockIdx.y;  // 0..7
    int idx = strip * 256 + threadIdx.x;
    if (idx < 1700) {
        const float* pp = ws + PPART_OFF + (size_t)bq * 128 * 1700 + idx;
        float a0 = 0.f, a1 = 0.f;
        #pragma unroll 4
        for (int win = 0; win < 128; win += 2) {
            a0 += pp[(size_t)win * 1700];
            a1 += pp[(size_t)(win + 1) * 1700];
        }
        ws[PQ_OFF + (size_t)bq * 1700 + idx] = a0 + a1;
    }
}

// ---------------- K3: rels + finalize (s-quarter split) ----------------
__global__ __launch_bounds__(256) void k_finalize(const float* __restrict__ spf1,
                                                  const float* __restrict__ spf2,
                                                  float* __restrict__ ws) {
    int sq = blockIdx.x;  // 0..3 (25 s each)
    int bq = blockIdx.y;  // 0..7
    int b = bq >> 1, q = bq & 1;
    __shared__ float sp[CC][SS];
    __shared__ float rl[25][SS + 1];
    __shared__ float Pl[CC * SS];
    __shared__ float qs[SS];
    __shared__ float den[25];
    int tid = threadIdx.x;

    const float* spf = (q ? spf2 : spf1) + (size_t)b * CC * SS;
    for (int i = tid; i < CC * SS; i += 256) sp[i / SS][i % SS] = spf[i];
    const float* pq = ws + PQ_OFF + (size_t)bq * 1700;
    for (int idx = tid; idx < CC * SS; idx += 256) {
        int c = idx / SS, t = idx % SS;
        Pl[idx] = pq[(size_t)t * 17 + c];
    }
    if (tid < SS) qs[tid] = pq[(size_t)tid * 17 + 16];
    __syncthreads();
    for (int i = tid; i < 25 * SS; i += 256) {
        int sl = i / SS, t = i % SS;
        int s = sq * 25 + sl;
        float d2 = 0.f;
        #pragma unroll
        for (int c = 0; c < CC; ++c) {
            float d = sp[c][t] - sp[c][s];
            d2 += d * d;
        }
        rl[sl][t] = expf(-d2);
    }
    __syncthreads();
    if (tid < 25) {
        float a = 0.f;
        for (int t = 0; t < SS; ++t) a += rl[tid][t] * qs[t];
        den[tid] = a + EPSV;
    }
    __syncthreads();
    float* sout = ws + SPFN_OFF + (size_t)bq * SS * CC;
    for (int idx = tid; idx < 25 * CC; idx += 256) {
        int sl = idx / CC, c = idx % CC;
        float a = 0.f;
        for (int t = 0; t < SS; ++t) a += rl[sl][t] * Pl[c * SS + t];
        sout[(size_t)(sq * 25 + sl) * CC + c] = a / den[sl];
    }
}

// ---------------- K4: pf_sp = spf1n@Q1 + spf2n@Q2 ----------------
#define P2STEP(V1, V2, s) { \
    _Pragma("unroll") for (int g = 0; g < 4; ++g) { \
        float4 s1 = *(const float4*)&spl[(0 * SS + (s)) * CC + g * 4]; \
        float4 s2 = *(const float4*)&spl[(SS + (s)) * CC + g * 4]; \
        acc[g*4+0].x += s1.x*V1.x + s2.x*V2.x; \
        acc[g*4+0].y += s1.x*V1.y + s2.x*V2.y; \
        acc[g*4+1].x += s1.y*V1.x + s2.y*V2.x; \
        acc[g*4+1].y += s1.y*V1.y + s2.y*V2.y; \
        acc[g*4+2].x += s1.z*V1.x + s2.z*V2.x; \
        acc[g*4+2].y += s1.z*V1.y + s2.z*V2.y; \
        acc[g*4+3].x += s1.w*V1.x + s2.w*V2.x; \
        acc[g*4+3].y += s1.w*V1.y + s2.w*V2.y; } }

__global__ __launch_bounds__(128) void k_pass2(const float* __restrict__ Q1,
                                               const float* __restrict__ Q2,
                                               float* __restrict__ ws) {
    int blk = blockIdx.x;   // 0..255
    int b   = blockIdx.y;
    __shared__ float spl[2 * SS * CC];
    int tid = threadIdx.x;
    const float* spin = ws + SPFN_OFF + (size_t)b * 2 * SS * CC;
    for (int idx = tid; idx < 2 * SS * CC; idx += 128) spl[idx] = spin[idx];
    __syncthreads();
    int n = blk * 256 + tid * 2;
    const float* q1p = Q1 + (size_t)b * SS * NN + n;
    const float* q2p = Q2 + (size_t)b * SS * NN + n;
    float2 acc[CC];
    #pragma unroll
    for (int c = 0; c < CC; ++c) acc[c] = make_float2(0.f, 0.f);
    float2 A1, A2, B1, B2;
    A1 = *(const float2*)(q1p);
    A2 = *(const float2*)(q2p);
    #pragma unroll 2
    for (int s = 0; s < 98; s += 2) {
        B1 = *(const float2*)(q1p + (size_t)(s + 1) * NN);
        B2 = *(const float2*)(q2p + (size_t)(s + 1) * NN);
        P2STEP(A1, A2, s)
        A1 = *(const float2*)(q1p + (size_t)(s + 2) * NN);
        A2 = *(const float2*)(q2p + (size_t)(s + 2) * NN);
        P2STEP(B1, B2, s + 1)
    }
    B1 = *(const float2*)(q1p + (size_t)99 * NN);
    B2 = *(const float2*)(q2p + (size_t)99 * NN);
    P2STEP(A1, A2, 98)
    P2STEP(B1, B2, 99)
    float* o = ws + PFSP_OFF + (size_t)b * CC * NN + n;
    #pragma unroll
    for (int c = 0; c < CC; ++c)
        *(float2*)(o + (size_t)c * NN) = acc[c];
}

// ---------------- K5: 3x3 conv, 16 -> 2 channels, + bias ----------------
__global__ __launch_bounds__(256) void k_conv(const float* __restrict__ w_ds,
                                              const float* __restrict__ b_ds,
                                              const float* __restrict__ ws,
                                              float* __restrict__ out) {
    int b = blockIdx.y;
    int n = blockIdx.x * 256 + threadIdx.x;
    __shared__ float wl[2][CC][9];
    __shared__ float bl[2];
    for (int i = threadIdx.x; i < 2 * CC * 9; i += 256)
        ((float*)wl)[i] = w_ds[i];
    if (threadIdx.x < 2) bl[threadIdx.x] = b_ds[threadIdx.x];
    __syncthreads();
    int y = n >> 8, x = n & 255;
    const float* base = ws + PFSP_OFF + (size_t)b * CC * NN;
    float a0 = bl[0], a1 = bl[1];
    for (int c = 0; c < CC; ++c) {
        const float* pc = base + (size_t)c * NN;
        #pragma unroll
        for (int dy = -1; dy <= 1; ++dy) {
            int yy = y + dy;
            if (yy < 0 || yy >= HH) continue;
            #pragma unroll
            for (int dx = -1; dx <= 1; ++dx) {
                int xx = x + dx;
                if (xx < 0 || xx >= WW) continue;
                float v = pc[(size_t)yy * WW + xx];
                int k = (dy + 1) * 3 + (dx + 1);
                a0 += v * wl[0][c][k];
                a1 += v * wl[1][c][k];
            }
        }
    }
    out[((size_t)b * 2 + 0) * NN + n] = a0;
    out[((size_t)b * 2 + 1) * NN + n] = a1;
}

extern "C" void kernel_launch(void* const* d_in, const int* in_sizes, int n_in,
                              void* d_out, int out_size, void* d_ws, size_t ws_size,
                              hipStream_t stream) {
    const float* pf   = (const float*)d_in[0];
    const float* spf1 = (const float*)d_in[1];
    const float* spf2 = (const float*)d_in[2];
    const float* Q1   = (const float*)d_in[3];
    const float* Q2   = (const float*)d_in[4];
    const float* w_ds = (const float*)d_in[5];
    const float* b_ds = (const float*)d_in[6];
    float* ws  = (float*)d_ws;
    float* out = (float*)d_out;

    k_pass1<<<dim3(128, 8), 256, 0, stream>>>(pf, Q1, Q2, ws);
    k_reduceP<<<dim3(7, 8), 256, 0, stream>>>(ws);
    k_finalize<<<dim3(4, 8), 256, 0, stream>>>(spf1, spf2, ws);
    k_pass2<<<dim3(256, BB), 128, 0, stream>>>(Q1, Q2, ws);
    k_conv<<<dim3(NN / 256, BB), 256, 0, stream>>>(w_ds, b_ds, ws, out);
}

// Round 26
// 131.787 us; speedup vs baseline: 1.1211x; 1.1211x over previous
//
#include <hip/hip_runtime.h>

// Problem constants
#define BB 4
#define CC 16
#define HH 256
#define WW 256
#define NN (HH*WW)      // 65536
#define SS 100
#define EPSV 1e-32f

// ws layout (float offsets)
#define PQ_OFF    0u                      // [8 bq][100 s][17]           = 13600
#define SPFN_OFF  13600u                  // [8 bq][100 s][16 c]         = 12800
#define PFSP_OFF  26400u                  // [4][16][65536]              = 4194304
#define PPART_OFF PFSP_OFF                // [8][64 chunk][100 s][17]    = 870400
// PPART aliases PFSP: consumed by k_reduceP before k_pass2 overwrites.

typedef _Float16 f16x8 __attribute__((ext_vector_type(8)));
typedef float f32x4 __attribute__((ext_vector_type(4)));
typedef __fp16 h2 __attribute__((ext_vector_type(2)));

// ---------------- pass1 (K1): canonical LDS-staged MFMA GEMM ----------------
// Best-measured configuration (R20/R24: total 132.3-133.6us). 1024-px
// chunks, 128-px stages, f16 LDS double-buffer (+8 pad), MFMA with ones-A
// qsum, wave owns s-tiles {wid, wid+4}. Q/pf issued exactly once.
#define LQROW(i) { int sl_ = (i) * 256 + tid; int r_ = sl_ >> 5; \
    if (r_ > 99) r_ = 99; qo##i = (size_t)r_ * NN + (sl_ & 31) * 4; }

#define LOADQ(ST) { int so_ = (ST) * 128; \
    lq0  = *(const float4*)(Qb + qo0  + so_); \
    lq1  = *(const float4*)(Qb + qo1  + so_); \
    lq2  = *(const float4*)(Qb + qo2  + so_); \
    lq3  = *(const float4*)(Qb + qo3  + so_); \
    lq4  = *(const float4*)(Qb + qo4  + so_); \
    lq5  = *(const float4*)(Qb + qo5  + so_); \
    lq6  = *(const float4*)(Qb + qo6  + so_); \
    lq7  = *(const float4*)(Qb + qo7  + so_); \
    lq8  = *(const float4*)(Qb + qo8  + so_); \
    lq9  = *(const float4*)(Qb + qo9  + so_); \
    lq10 = *(const float4*)(Qb + qo10 + so_); \
    lq11 = *(const float4*)(Qb + qo11 + so_); \
    lq12 = *(const float4*)(Qb + qo12 + so_); \
    lp0  = *(const float4*)(Pb + po0  + so_); \
    lp1  = *(const float4*)(Pb + po1  + so_); }

#define W1(DST, i, R) { int sl_ = (i) * 256 + tid; \
    int w_ = (sl_ >> 5) * 136 + (sl_ & 31) * 4; \
    *(h2*)&DST[w_]     = __builtin_amdgcn_cvt_pkrtz(R.x, R.y); \
    *(h2*)&DST[w_ + 2] = __builtin_amdgcn_cvt_pkrtz(R.z, R.w); }

#define CVTW(QL, FL) { \
    W1(QL, 0, lq0)  W1(QL, 1, lq1)  W1(QL, 2, lq2)  W1(QL, 3, lq3) \
    W1(QL, 4, lq4)  W1(QL, 5, lq5)  W1(QL, 6, lq6)  W1(QL, 7, lq7) \
    W1(QL, 8, lq8)  W1(QL, 9, lq9)  W1(QL, 10, lq10) W1(QL, 11, lq11) \
    W1(QL, 12, lq12) W1(FL, 0, lp0) W1(FL, 1, lp1) }

#define KSTEP(QL, FL, J) { \
    f16x8 af = *(const f16x8*)&FL[aoff + (J) * 32]; \
    f16x8 b0 = *(const f16x8*)&QL[boff0 + (J) * 32]; \
    f16x8 b1 = *(const f16x8*)&QL[boff1 + (J) * 32]; \
    acc0 = __builtin_amdgcn_mfma_f32_16x16x32_f16(af, b0, acc0, 0, 0, 0); \
    qac0 = __builtin_amdgcn_mfma_f32_16x16x32_f16(ones, b0, qac0, 0, 0, 0); \
    acc1 = __builtin_amdgcn_mfma_f32_16x16x32_f16(af, b1, acc1, 0, 0, 0); \
    qac1 = __builtin_amdgcn_mfma_f32_16x16x32_f16(ones, b1, qac1, 0, 0, 0); }

#define CMP(QL, FL) { KSTEP(QL, FL, 0) KSTEP(QL, FL, 1) \
                      KSTEP(QL, FL, 2) KSTEP(QL, FL, 3) }

__global__ __launch_bounds__(256, 2) void k_pass1(const float* __restrict__ pf,
                                                  const float* __restrict__ Q1,
                                                  const float* __restrict__ Q2,
                                                  float* __restrict__ ws) {
    int tid = threadIdx.x, wid = tid >> 6, lane = tid & 63;
    int chunk = blockIdx.x;    // 0..63 (1024-px chunk)
    int bq    = blockIdx.y;    // 0..7
    int b = bq >> 1, q = bq & 1;
    int r16 = lane & 15, g4 = lane >> 4;
    int n0 = chunk * 1024;

    const float* Qb = (q ? Q2 : Q1) + (size_t)b * SS * NN + n0;
    const float* Pb = pf + (size_t)b * CC * NN + n0;

    __shared__ __align__(16) __fp16 qldsA[112 * 136];   // 29.75 KB
    __shared__ __align__(16) __fp16 qldsB[112 * 136];
    __shared__ __align__(16) __fp16 fldsA[16 * 136];    // 4.25 KB
    __shared__ __align__(16) __fp16 fldsB[16 * 136];

    // staging offsets (per-thread, stage-invariant)
    size_t qo0, qo1, qo2, qo3, qo4, qo5, qo6, qo7, qo8, qo9, qo10, qo11, qo12;
    LQROW(0) LQROW(1) LQROW(2) LQROW(3) LQROW(4) LQROW(5) LQROW(6)
    LQROW(7) LQROW(8) LQROW(9) LQROW(10) LQROW(11) LQROW(12)
    size_t po0, po1;
    { int sl = tid;       po0 = (size_t)(sl >> 5) * NN + (sl & 31) * 4; }
    { int sl = 256 + tid; po1 = (size_t)(sl >> 5) * NN + (sl & 31) * 4; }

    // MFMA fragment LDS offsets (f16 units)
    int t0 = wid;
    int t1 = (wid < 3) ? wid + 4 : 3;
    int aoff  = r16 * 136 + g4 * 8;
    int boff0 = (t0 * 16 + r16) * 136 + g4 * 8;
    int boff1 = (t1 * 16 + r16) * 136 + g4 * 8;

    f32x4 acc0 = {0.f, 0.f, 0.f, 0.f}, acc1 = {0.f, 0.f, 0.f, 0.f};
    f32x4 qac0 = {0.f, 0.f, 0.f, 0.f}, qac1 = {0.f, 0.f, 0.f, 0.f};
    const f16x8 ones = {1.f16, 1.f16, 1.f16, 1.f16, 1.f16, 1.f16, 1.f16, 1.f16};

    float4 lq0, lq1, lq2, lq3, lq4, lq5, lq6, lq7, lq8, lq9, lq10, lq11, lq12;
    float4 lp0, lp1;

    LOADQ(0) CVTW(qldsA, fldsA) __syncthreads();
    LOADQ(1) CMP(qldsA, fldsA) CVTW(qldsB, fldsB) __syncthreads();  // st0
    LOADQ(2) CMP(qldsB, fldsB) CVTW(qldsA, fldsA) __syncthreads();  // st1
    LOADQ(3) CMP(qldsA, fldsA) CVTW(qldsB, fldsB) __syncthreads();  // st2
    LOADQ(4) CMP(qldsB, fldsB) CVTW(qldsA, fldsA) __syncthreads();  // st3
    LOADQ(5) CMP(qldsA, fldsA) CVTW(qldsB, fldsB) __syncthreads();  // st4
    LOADQ(6) CMP(qldsB, fldsB) CVTW(qldsA, fldsA) __syncthreads();  // st5
    LOADQ(7) CMP(qldsA, fldsA) CVTW(qldsB, fldsB) __syncthreads();  // st6
    CMP(qldsB, fldsB)                                               // st7

    float* sout = ws + PPART_OFF + (size_t)(bq * 64 + chunk) * 1700;
    {
        int s0 = t0 * 16 + r16;            // 0..63, always valid
        float* o = sout + (size_t)s0 * 17 + g4 * 4;
        o[0] = acc0[0]; o[1] = acc0[1]; o[2] = acc0[2]; o[3] = acc0[3];
        if (lane < 16) sout[(size_t)s0 * 17 + 16] = qac0[0];
    }
    if (wid < 3) {
        int s1 = (wid + 4) * 16 + r16;     // 64..111
        if (s1 < 100) {
            float* o = sout + (size_t)s1 * 17 + g4 * 4;
            o[0] = acc1[0]; o[1] = acc1[1]; o[2] = acc1[2]; o[3] = acc1[3];
            if (lane < 16) sout[(size_t)s1 * 17 + 16] = qac1[0];
        }
    }
}

// ---------------- K2: reduce over 64 chunks (coalesced) ----------------
__global__ __launch_bounds__(256) void k_reduceP(float* __restrict__ ws) {
    int strip = blockIdx.x;  // 0..6
    int bq    = blockIdx.y;  // 0..7
    int idx = strip * 256 + threadIdx.x;
    if (idx < 1700) {
        const float* pp = ws + PPART_OFF + (size_t)bq * 64 * 1700 + idx;
        float a0 = 0.f, a1 = 0.f;
        #pragma unroll 4
        for (int win = 0; win < 64; win += 2) {
            a0 += pp[(size_t)win * 1700];
            a1 += pp[(size_t)(win + 1) * 1700];
        }
        ws[PQ_OFF + (size_t)bq * 1700 + idx] = a0 + a1;
    }
}

// ---------------- K3: rels + finalize (s-quarter split) ----------------
__global__ __launch_bounds__(256) void k_finalize(const float* __restrict__ spf1,
                                                  const float* __restrict__ spf2,
                                                  float* __restrict__ ws) {
    int sq = blockIdx.x;  // 0..3 (25 s each)
    int bq = blockIdx.y;  // 0..7
    int b = bq >> 1, q = bq & 1;
    __shared__ float sp[CC][SS];
    __shared__ float rl[25][SS + 1];
    __shared__ float Pl[CC * SS];
    __shared__ float qs[SS];
    __shared__ float den[25];
    int tid = threadIdx.x;

    const float* spf = (q ? spf2 : spf1) + (size_t)b * CC * SS;
    for (int i = tid; i < CC * SS; i += 256) sp[i / SS][i % SS] = spf[i];
    const float* pq = ws + PQ_OFF + (size_t)bq * 1700;
    for (int idx = tid; idx < CC * SS; idx += 256) {
        int c = idx / SS, t = idx % SS;
        Pl[idx] = pq[(size_t)t * 17 + c];
    }
    if (tid < SS) qs[tid] = pq[(size_t)tid * 17 + 16];
    __syncthreads();
    for (int i = tid; i < 25 * SS; i += 256) {
        int sl = i / SS, t = i % SS;
        int s = sq * 25 + sl;
        float d2 = 0.f;
        #pragma unroll
        for (int c = 0; c < CC; ++c) {
            float d = sp[c][t] - sp[c][s];
            d2 += d * d;
        }
        rl[sl][t] = expf(-d2);
    }
    __syncthreads();
    if (tid < 25) {
        float a = 0.f;
        for (int t = 0; t < SS; ++t) a += rl[tid][t] * qs[t];
        den[tid] = a + EPSV;
    }
    __syncthreads();
    float* sout = ws + SPFN_OFF + (size_t)bq * SS * CC;
    for (int idx = tid; idx < 25 * CC; idx += 256) {
        int sl = idx / CC, c = idx % CC;
        float a = 0.f;
        for (int t = 0; t < SS; ++t) a += rl[sl][t] * Pl[c * SS + t];
        sout[(size_t)(sq * 25 + sl) * CC + c] = a / den[sl];
    }
}

// ---------------- K4: pf_sp = spf1n@Q1 + spf2n@Q2 ----------------
#define P2STEP(V1, V2, s) { \
    _Pragma("unroll") for (int g = 0; g < 4; ++g) { \
        float4 s1 = *(const float4*)&spl[(0 * SS + (s)) * CC + g * 4]; \
        float4 s2 = *(const float4*)&spl[(SS + (s)) * CC + g * 4]; \
        acc[g*4+0].x += s1.x*V1.x + s2.x*V2.x; \
        acc[g*4+0].y += s1.x*V1.y + s2.x*V2.y; \
        acc[g*4+1].x += s1.y*V1.x + s2.y*V2.x; \
        acc[g*4+1].y += s1.y*V1.y + s2.y*V2.y; \
        acc[g*4+2].x += s1.z*V1.x + s2.z*V2.x; \
        acc[g*4+2].y += s1.z*V1.y + s2.z*V2.y; \
        acc[g*4+3].x += s1.w*V1.x + s2.w*V2.x; \
        acc[g*4+3].y += s1.w*V1.y + s2.w*V2.y; } }

__global__ __launch_bounds__(128) void k_pass2(const float* __restrict__ Q1,
                                               const float* __restrict__ Q2,
                                               float* __restrict__ ws) {
    int blk = blockIdx.x;   // 0..255
    int b   = blockIdx.y;
    __shared__ float spl[2 * SS * CC];
    int tid = threadIdx.x;
    const float* spin = ws + SPFN_OFF + (size_t)b * 2 * SS * CC;
    for (int idx = tid; idx < 2 * SS * CC; idx += 128) spl[idx] = spin[idx];
    __syncthreads();
    int n = blk * 256 + tid * 2;
    const float* q1p = Q1 + (size_t)b * SS * NN + n;
    const float* q2p = Q2 + (size_t)b * SS * NN + n;
    float2 acc[CC];
    #pragma unroll
    for (int c = 0; c < CC; ++c) acc[c] = make_float2(0.f, 0.f);
    float2 A1, A2, B1, B2;
    A1 = *(const float2*)(q1p);
    A2 = *(const float2*)(q2p);
    #pragma unroll 2
    for (int s = 0; s < 98; s += 2) {
        B1 = *(const float2*)(q1p + (size_t)(s + 1) * NN);
        B2 = *(const float2*)(q2p + (size_t)(s + 1) * NN);
        P2STEP(A1, A2, s)
        A1 = *(const float2*)(q1p + (size_t)(s + 2) * NN);
        A2 = *(const float2*)(q2p + (size_t)(s + 2) * NN);
        P2STEP(B1, B2, s + 1)
    }
    B1 = *(const float2*)(q1p + (size_t)99 * NN);
    B2 = *(const float2*)(q2p + (size_t)99 * NN);
    P2STEP(A1, A2, 98)
    P2STEP(B1, B2, 99)
    float* o = ws + PFSP_OFF + (size_t)b * CC * NN + n;
    #pragma unroll
    for (int c = 0; c < CC; ++c)
        *(float2*)(o + (size_t)c * NN) = acc[c];
}

// ---------------- K5: 3x3 conv, 16 -> 2 channels, + bias ----------------
__global__ __launch_bounds__(256) void k_conv(const float* __restrict__ w_ds,
                                              const float* __restrict__ b_ds,
                                              const float* __restrict__ ws,
                                              float* __restrict__ out) {
    int b = blockIdx.y;
    int n = blockIdx.x * 256 + threadIdx.x;
    __shared__ float wl[2][CC][9];
    __shared__ float bl[2];
    for (int i = threadIdx.x; i < 2 * CC * 9; i += 256)
        ((float*)wl)[i] = w_ds[i];
    if (threadIdx.x < 2) bl[threadIdx.x] = b_ds[threadIdx.x];
    __syncthreads();
    int y = n >> 8, x = n & 255;
    const float* base = ws + PFSP_OFF + (size_t)b * CC * NN;
    float a0 = bl[0], a1 = bl[1];
    for (int c = 0; c < CC; ++c) {
        const float* pc = base + (size_t)c * NN;
        #pragma unroll
        for (int dy = -1; dy <= 1; ++dy) {
            int yy = y + dy;
            if (yy < 0 || yy >= HH) continue;
            #pragma unroll
            for (int dx = -1; dx <= 1; ++dx) {
                int xx = x + dx;
                if (xx < 0 || xx >= WW) continue;
                float v = pc[(size_t)yy * WW + xx];
                int k = (dy + 1) * 3 + (dx + 1);
                a0 += v * wl[0][c][k];
                a1 += v * wl[1][c][k];
            }
        }
    }
    out[((size_t)b * 2 + 0) * NN + n] = a0;
    out[((size_t)b * 2 + 1) * NN + n] = a1;
}

extern "C" void kernel_launch(void* const* d_in, const int* in_sizes, int n_in,
                              void* d_out, int out_size, void* d_ws, size_t ws_size,
                              hipStream_t stream) {
    const float* pf   = (const float*)d_in[0];
    const float* spf1 = (const float*)d_in[1];
    const float* spf2 = (const float*)d_in[2];
    const float* Q1   = (const float*)d_in[3];
    const float* Q2   = (const float*)d_in[4];
    const float* w_ds = (const float*)d_in[5];
    const float* b_ds = (const float*)d_in[6];
    float* ws  = (float*)d_ws;
    float* out = (float*)d_out;

    k_pass1<<<dim3(64, 8), 256, 0, stream>>>(pf, Q1, Q2, ws);
    k_reduceP<<<dim3(7, 8), 256, 0, stream>>>(ws);
    k_finalize<<<dim3(4, 8), 256, 0, stream>>>(spf1, spf2, ws);
    k_pass2<<<dim3(256, BB), 128, 0, stream>>>(Q1, Q2, ws);
    k_conv<<<dim3(NN / 256, BB), 256, 0, stream>>>(w_ds, b_ds, ws, out);
}